// Round 1
// 988.458 us; speedup vs baseline: 1.0095x; 1.0095x over previous
//
#include <hip/hip_runtime.h>

// ---------------------------------------------------------------------------
// MultiHeadAttention: B=2, S=2048, D=1024, H=16, DEPTH=64
// out  = (2, 2047, 1024) fp32   att = (2, 16, 2047, 2047) fp32
// bf16x3 split MFMA for Q/K path; plain bf16 for V/O path.
// All heavy staging via __builtin_amdgcn_global_load_lds (16B), chunk-major
// LDS layout [k-chunk][row] => lane-linear DMA + conflict-free ds_read_b128.
// R1: attn 2-phase double-buffered staging (T3-min), exp2 softmax, float4 tail.
// ---------------------------------------------------------------------------

typedef __attribute__((ext_vector_type(8))) short bf16x8;
typedef __attribute__((ext_vector_type(4))) float f32x4;

#define MFMA_BF16(A, B, C) __builtin_amdgcn_mfma_f32_16x16x32_bf16(A, B, C, 0, 0, 0)

__device__ __forceinline__ short f2bf(float x) {
    unsigned u = __float_as_uint(x);
    u = u + 0x7FFFu + ((u >> 16) & 1u);   // RNE
    return (short)(u >> 16);
}
__device__ __forceinline__ float bf2f(short s) {
    return __uint_as_float(((unsigned)(unsigned short)s) << 16);
}
__device__ __forceinline__ int imin(int a, int b) { return a < b ? a : b; }

// scores are pre-scaled by log2(e)/8, so softmax exp == exp2
__device__ __forceinline__ float fexp2(float x) {
#if __has_builtin(__builtin_amdgcn_exp2f)
    return __builtin_amdgcn_exp2f(x);
#else
    return __expf(x * 0.69314718055994531f);
#endif
}

// async global->LDS, 16B per lane; lds ptr per-lane = wave base + lane*16
__device__ __forceinline__ void dma16(const short* g, short* l) {
    __builtin_amdgcn_global_load_lds(
        (const __attribute__((address_space(1))) unsigned int*)g,
        (__attribute__((address_space(3))) unsigned int*)l, 16, 0, 0);
}

// ---------------------------------------------------------------------------
// Transpose 1024x1024 W -> T[n][k] = W[k][n], split into bf16 hi (+ opt lo)
// ---------------------------------------------------------------------------
__global__ __launch_bounds__(256) void transpose_split_kernel(
    const float* __restrict__ W, short* __restrict__ Thi, short* __restrict__ Tlo) {
    __shared__ float tile[32][33];
    const int tx = threadIdx.x & 31, ty = threadIdx.x >> 5;
    const int k0 = blockIdx.x * 32, n0 = blockIdx.y * 32;
#pragma unroll
    for (int p = 0; p < 4; ++p)
        tile[ty + p * 8][tx] = W[(size_t)(k0 + ty + p * 8) * 1024 + n0 + tx];
    __syncthreads();
#pragma unroll
    for (int p = 0; p < 4; ++p) {
        int n = n0 + ty + p * 8, k = k0 + tx;
        float x = tile[tx][ty + p * 8];
        short h = f2bf(x);
        Thi[(size_t)n * 1024 + k] = h;
        if (Tlo) Tlo[(size_t)n * 1024 + k] = f2bf(x - bf2f(h));
    }
}

// ---------------------------------------------------------------------------
// fp32 -> bf16 hi (+ optional lo) elementwise split, 8 elems/thread
// ---------------------------------------------------------------------------
__global__ __launch_bounds__(256) void split_kernel(
    const float* __restrict__ X, short* __restrict__ Hi, short* __restrict__ Lo, int n8) {
    int idx = blockIdx.x * 256 + threadIdx.x;
    if (idx >= n8) return;
    float4 x0 = *((const float4*)X + (size_t)idx * 2);
    float4 x1 = *((const float4*)X + (size_t)idx * 2 + 1);
    float xs[8] = {x0.x, x0.y, x0.z, x0.w, x1.x, x1.y, x1.z, x1.w};
    bf16x8 hv, lv;
#pragma unroll
    for (int e = 0; e < 8; ++e) {
        short h = f2bf(xs[e]);
        hv[e] = h;
        lv[e] = f2bf(xs[e] - bf2f(h));
    }
    *(bf16x8*)&Hi[(size_t)idx * 8] = hv;
    if (Lo) *(bf16x8*)&Lo[(size_t)idx * 8] = lv;
}

// ---------------------------------------------------------------------------
// GEMM: C[M x 1024] = A[M x 1024] @ Bt^T + bias  (Bt[n][k] pre-transposed)
// A, Bt in bf16 (hi and, if SPLIT, lo). Tile 128(M) x 64(N), BK=32.
// 256 threads / 4 waves, wave quadrant 64x32 = 4x2 frags of 16x16x32.
// LDS chunk-major: A [c=4][row=128], B [c=4][row=64]; DMA lane-linear.
// OUTMODE: 0 = fp32 Cf, 1 = bf16 Chi, 2 = bf16 hi/lo (scaled).
// ---------------------------------------------------------------------------
template <int SPLIT, int OUTMODE>
__global__ __launch_bounds__(256) void gemm_dma(
    const short* __restrict__ Ahg, const short* __restrict__ Alg, int M,
    const short* __restrict__ Bhg, const short* __restrict__ Blg,
    const float* __restrict__ bias, float scale,
    float* __restrict__ Cf, short* __restrict__ Chi, short* __restrict__ Clo) {
    __shared__ __align__(16) short Ah[512 * 8];
    __shared__ __align__(16) short Al[SPLIT ? 512 * 8 : 8];
    __shared__ __align__(16) short Bh[256 * 8];
    __shared__ __align__(16) short Bl[SPLIT ? 256 * 8 : 8];

    const int tid = threadIdx.x;
    const int w = tid >> 6, lane = tid & 63;
    const int quad = lane >> 4, l16 = lane & 15;
    const int m0 = blockIdx.y * 128, n0 = blockIdx.x * 64;
    const int row0 = (w & 1) * 64, col0 = (w >> 1) * 32;

    f32x4 acc[4][2];
#pragma unroll
    for (int mi = 0; mi < 4; ++mi)
#pragma unroll
        for (int ni = 0; ni < 2; ++ni) acc[mi][ni] = (f32x4){0.f, 0.f, 0.f, 0.f};

    const int a_row = tid & 127;
    const int a_gr = imin(m0 + a_row, M - 1);
    const int b_gr = n0 + (tid & 63);
    const int b_c = tid >> 6;

    for (int k0 = 0; k0 < 1024; k0 += 32) {
        __syncthreads();
#pragma unroll
        for (int p = 0; p < 2; ++p) {
            int c = (p * 256 + tid) >> 7;
            const size_t go = (size_t)a_gr * 1024 + k0 + c * 8;
            dma16(Ahg + go, &Ah[(p * 256 + tid) * 8]);
            if (SPLIT) dma16(Alg + go, &Al[(p * 256 + tid) * 8]);
        }
        {
            const size_t go = (size_t)b_gr * 1024 + k0 + b_c * 8;
            dma16(Bhg + go, &Bh[tid * 8]);
            if (SPLIT) dma16(Blg + go, &Bl[tid * 8]);
        }
        __syncthreads();

        bf16x8 af[4], afl[4], bfr[2], bfl[2];
#pragma unroll
        for (int mi = 0; mi < 4; ++mi) {
            int r = row0 + mi * 16 + l16;
            af[mi] = *(const bf16x8*)&Ah[(quad * 128 + r) * 8];
            if (SPLIT) afl[mi] = *(const bf16x8*)&Al[(quad * 128 + r) * 8];
        }
#pragma unroll
        for (int ni = 0; ni < 2; ++ni) {
            int cdx = col0 + ni * 16 + l16;
            bfr[ni] = *(const bf16x8*)&Bh[(quad * 64 + cdx) * 8];
            if (SPLIT) bfl[ni] = *(const bf16x8*)&Bl[(quad * 64 + cdx) * 8];
        }
#pragma unroll
        for (int mi = 0; mi < 4; ++mi)
#pragma unroll
            for (int ni = 0; ni < 2; ++ni) {
                acc[mi][ni] = MFMA_BF16(af[mi], bfr[ni], acc[mi][ni]);
                if (SPLIT) {
                    acc[mi][ni] = MFMA_BF16(af[mi], bfl[ni], acc[mi][ni]);
                    acc[mi][ni] = MFMA_BF16(afl[mi], bfr[ni], acc[mi][ni]);
                }
            }
    }

#pragma unroll
    for (int ni = 0; ni < 2; ++ni) {
        int col = n0 + col0 + ni * 16 + l16;
        float bv = bias[col];
#pragma unroll
        for (int mi = 0; mi < 4; ++mi) {
#pragma unroll
            for (int r = 0; r < 4; ++r) {
                int row = m0 + row0 + mi * 16 + quad * 4 + r;
                if (row < M) {
                    float c = (acc[mi][ni][r] + bv) * scale;
                    size_t off = (size_t)row * 1024 + col;
                    if (OUTMODE == 0) {
                        Cf[off] = c;
                    } else if (OUTMODE == 1) {
                        Chi[off] = f2bf(c);
                    } else {
                        short h = f2bf(c);
                        Chi[off] = h;
                        Clo[off] = f2bf(c - bf2f(h));
                    }
                }
            }
        }
    }
}

// ---------------------------------------------------------------------------
// VV [ (b*2047+seq)*1024 + h*64 + d ] -> VT [ ((b*16+h)*64+d)*2048 + seq ]
// (row pad to 2048; pad col written as 0)
// ---------------------------------------------------------------------------
__global__ __launch_bounds__(256) void transpose_v_kernel(
    const short* __restrict__ VV, short* __restrict__ VT) {
    __shared__ short t[64][72];
    const int tid = threadIdx.x;
    const int st = blockIdx.x & 31, bh = blockIdx.x >> 5;
    const int b = bh >> 4, h = bh & 15;
    const int s0 = st * 64;
    {
        int seq = s0 + (tid >> 2), d0 = (tid & 3) * 16;
        int seqc = imin(seq, 2046);
        const short* src = VV + ((size_t)(b * 2047 + seqc)) * 1024 + h * 64 + d0;
        bf16x8 v0 = *(const bf16x8*)src;
        bf16x8 v1 = *(const bf16x8*)(src + 8);
        bool ok = (seq <= 2046);
#pragma unroll
        for (int e = 0; e < 8; ++e) {
            t[d0 + e][tid >> 2] = ok ? v0[e] : (short)0;
            t[d0 + 8 + e][tid >> 2] = ok ? v1[e] : (short)0;
        }
    }
    __syncthreads();
    {
        int d = tid >> 2, sc2 = (tid & 3) * 16;
        bf16x8 o0, o1;
#pragma unroll
        for (int e = 0; e < 8; ++e) {
            o0[e] = t[d][sc2 + e];
            o1[e] = t[d][sc2 + 8 + e];
        }
        short* dst = VT + ((size_t)(bh * 64 + d)) * 2048 + s0 + sc2;
        *(bf16x8*)dst = o0;
        *(bf16x8*)(dst + 8) = o1;
    }
}

// ---------------------------------------------------------------------------
// Fused causal attention. QQ pre-scaled by log2(e)/8 and split hi/lo; KK split.
// att[b,h,i,j] = softmax_{j<=i}( QQ[b,i+1,h]·KK[b,j,h] ), ctx -> CTX (bf16).
// Block = 64 q-rows (4 waves x 16). 64-key tiles, two passes.
// Pass A (denominators): K-hi only. Pass B: full split + att write + PV.
// 2-phase double-buffered staging: prefetch tile t+1 before computing tile t,
// single __syncthreads per tile (implicit vmcnt(0) drains prefetch AFTER it
// has been hidden under compute). LDS 57 KB -> 2 blocks/CU.
// ---------------------------------------------------------------------------
__global__ __launch_bounds__(256) void attn_kernel(
    const short* __restrict__ QQh, const short* __restrict__ QQl,
    const short* __restrict__ KKh, const short* __restrict__ KKl,
    const short* __restrict__ VT,
    float* __restrict__ att, short* __restrict__ CTX) {
    __shared__ __align__(16) short KH[2][512 * 8];   // [buf][cc=8][key=64]
    __shared__ __align__(16) short KL[2][512 * 8];
    __shared__ __align__(16) short VS[2][512 * 8];   // [buf][kc=8][d=64]
    __shared__ __align__(16) short Ps[4][16 * 72];

    const int tid = threadIdx.x;
    const int w = tid >> 6, lane = tid & 63;
    const int quad = lane >> 4, l16 = lane & 15;
    const int bx = blockIdx.x;
    const int qt = 31 - (bx >> 5);          // global work-descending order
    const int bh = bx & 31;
    const int h = bh & 15, b = bh >> 4;
    const int i0 = qt * 64;

    const int i_frag = i0 + w * 16 + l16;
    const int qrow = imin(i_frag + 1, 2047);
    const size_t qoff = ((size_t)(b * 2048 + qrow)) * 1024 + h * 64;
    const bf16x8 qh0 = *(const bf16x8*)&QQh[qoff + 0 + quad * 8];
    const bf16x8 qh1 = *(const bf16x8*)&QQh[qoff + 32 + quad * 8];
    const bf16x8 ql0 = *(const bf16x8*)&QQl[qoff + 0 + quad * 8];
    const bf16x8 ql1 = *(const bf16x8*)&QQl[qoff + 32 + quad * 8];

    const int i_max = imin(i0 + 63, 2046);
    const int jt_max = i_max >> 6;
    const int wave_imax = imin(i0 + w * 16 + 15, 2046);
    const int rowbase = i0 + w * 16 + quad * 4;

    const int dma_key = tid & 63;
    const int dma_cc0 = tid >> 6;

    float lsum[4] = {0.f, 0.f, 0.f, 0.f};

    auto stageA = [&](int jt, int buf) {
#pragma unroll
        for (int p = 0; p < 2; ++p) {
            int cc = p * 4 + dma_cc0;
            dma16(KKh + ((size_t)(b * 2048 + jt * 64 + dma_key)) * 1024 + h * 64 + cc * 8,
                  &KH[buf][(p * 256 + tid) * 8]);
        }
    };
    auto stageB = [&](int jt, int buf) {
#pragma unroll
        for (int p = 0; p < 2; ++p) {
            int cc = p * 4 + dma_cc0;
            const size_t ko =
                ((size_t)(b * 2048 + jt * 64 + dma_key)) * 1024 + h * 64 + cc * 8;
            dma16(KKh + ko, &KH[buf][(p * 256 + tid) * 8]);
            dma16(KKl + ko, &KL[buf][(p * 256 + tid) * 8]);
            dma16(VT + ((size_t)(bh * 64 + dma_key)) * 2048 + jt * 64 + cc * 8,
                  &VS[buf][(p * 256 + tid) * 8]);
        }
    };

    // ---------------- PASS A: softmax denominators (K-hi only) --------------
    stageA(0, 0);
    __syncthreads();
    int cur = 0;
    for (int jt = 0; jt <= jt_max; ++jt) {
        if (jt < jt_max) stageA(jt + 1, cur ^ 1);
        const int j0 = jt * 64;
        if (j0 <= wave_imax) {
#pragma unroll
            for (int s = 0; s < 4; ++s) {
                f32x4 sc = (f32x4){0.f, 0.f, 0.f, 0.f};
#pragma unroll
                for (int c = 0; c < 2; ++c) {
                    bf16x8 kh =
                        *(const bf16x8*)&KH[cur][((c * 4 + quad) * 64 + s * 16 + l16) * 8];
                    sc = MFMA_BF16(c ? qh1 : qh0, kh, sc);
                    sc = MFMA_BF16(c ? ql1 : ql0, kh, sc);
                }
                int j = j0 + s * 16 + l16;
#pragma unroll
                for (int r = 0; r < 4; ++r) {
                    int i = rowbase + r;
                    if (j <= i && i <= 2046) lsum[r] += fexp2(sc[r]);
                }
            }
        }
        __syncthreads();
        cur ^= 1;
    }
#pragma unroll
    for (int m = 1; m < 16; m <<= 1) {
#pragma unroll
        for (int r = 0; r < 4; ++r) lsum[r] += __shfl_xor(lsum[r], m, 64);
    }
    float linv[4];
#pragma unroll
    for (int r = 0; r < 4; ++r) linv[r] = 1.0f / lsum[r];

    f32x4 cacc[4];
#pragma unroll
    for (int t = 0; t < 4; ++t) cacc[t] = (f32x4){0.f, 0.f, 0.f, 0.f};

    // ---------------- PASS B: att writes + PV -------------------------------
    stageB(0, 0);
    __syncthreads();
    cur = 0;
    for (int jt = 0; jt <= jt_max; ++jt) {
        if (jt < jt_max) stageB(jt + 1, cur ^ 1);
        const int j0 = jt * 64;
        if (j0 <= wave_imax) {
#pragma unroll
            for (int s = 0; s < 4; ++s) {
                f32x4 sc = (f32x4){0.f, 0.f, 0.f, 0.f};
#pragma unroll
                for (int c = 0; c < 2; ++c) {
                    const int ci = ((c * 4 + quad) * 64 + s * 16 + l16) * 8;
                    bf16x8 kh = *(const bf16x8*)&KH[cur][ci];
                    bf16x8 kl = *(const bf16x8*)&KL[cur][ci];
                    bf16x8 ah = c ? qh1 : qh0;
                    bf16x8 al = c ? ql1 : ql0;
                    sc = MFMA_BF16(ah, kh, sc);
                    sc = MFMA_BF16(ah, kl, sc);
                    sc = MFMA_BF16(al, kh, sc);
                }
                int j = j0 + s * 16 + l16;
#pragma unroll
                for (int r = 0; r < 4; ++r) {
                    int i = rowbase + r;
                    bool valid = (j <= i) && (i <= 2046);
                    float p = valid ? fexp2(sc[r]) * linv[r] : 0.0f;
                    if (i <= 2046 && j <= 2046)
                        att[((size_t)bh * 2047 + i) * 2047 + j] = p;
                    Ps[w][(quad * 4 + r) * 72 + s * 16 + l16] = f2bf(p);
                }
            }
#pragma unroll
            for (int c = 0; c < 2; ++c) {
                bf16x8 pa = *(const bf16x8*)&Ps[w][l16 * 72 + c * 32 + quad * 8];
#pragma unroll
                for (int t = 0; t < 4; ++t) {
                    bf16x8 vb =
                        *(const bf16x8*)&VS[cur][((c * 4 + quad) * 64 + t * 16 + l16) * 8];
                    cacc[t] = MFMA_BF16(pa, vb, cacc[t]);
                }
            }
        } else {
#pragma unroll
            for (int s = 0; s < 4; ++s) {
                int j = j0 + s * 16 + l16;
#pragma unroll
                for (int r = 0; r < 4; ++r) {
                    int i = rowbase + r;
                    if (i <= 2046 && j <= 2046)
                        att[((size_t)bh * 2047 + i) * 2047 + j] = 0.0f;
                }
            }
        }
        __syncthreads();
        cur ^= 1;
    }

    // ctx -> CTX (bf16)
#pragma unroll
    for (int t = 0; t < 4; ++t) {
#pragma unroll
        for (int r = 0; r < 4; ++r) {
            int i = rowbase + r;
            if (i <= 2046)
                CTX[((size_t)(b * 2047 + i)) * 1024 + h * 64 + t * 16 + l16] = f2bf(cacc[t][r]);
        }
    }

    // zero tail: att cols beyond the block's causal tiles (float4 vectorized)
    const int js = (jt_max + 1) * 64;
    if (js < 2047) {
        const float4 z4 = {0.f, 0.f, 0.f, 0.f};
        for (int i = i0; i <= i_max; ++i) {
            const size_t base = (size_t)(bh * 2047 + i) * 2047;
            float* rowp = att + base;
            int aligned = js + (int)((4 - ((base + js) & 3)) & 3);
            if (aligned > 2047) aligned = 2047;
            for (int c = js + tid; c < aligned; c += 256) rowp[c] = 0.0f;
            int nv = (2047 - aligned) >> 2;
            for (int q = tid; q < nv; q += 256)
                *(float4*)(rowp + aligned + q * 4) = z4;
            for (int c = aligned + nv * 4 + tid; c < 2047; c += 256) rowp[c] = 0.0f;
        }
    }
}

// ---------------------------------------------------------------------------
extern "C" void kernel_launch(void* const* d_in, const int* in_sizes, int n_in,
                              void* d_out, int out_size, void* d_ws, size_t ws_size,
                              hipStream_t stream) {
    (void)in_sizes; (void)n_in; (void)out_size; (void)ws_size;
    const float* q  = (const float*)d_in[0];
    const float* k  = (const float*)d_in[1];
    const float* v  = (const float*)d_in[2];
    const float* Wq = (const float*)d_in[4];
    const float* bq = (const float*)d_in[5];
    const float* Wk = (const float*)d_in[6];
    const float* bk = (const float*)d_in[7];
    const float* Wv = (const float*)d_in[8];
    const float* bv = (const float*)d_in[9];
    const float* Wo = (const float*)d_in[10];
    const float* bo = (const float*)d_in[11];

    float* out = (float*)d_out;                     // 2*2047*1024
    float* att = out + (size_t)2 * 2047 * 1024;     // 2*16*2047*2047

    char* ws = (char*)d_ws;
    size_t off = 0;
    auto alloc = [&](size_t bytes) -> void* {
        void* p = ws + off;
        off += (bytes + 255) & ~(size_t)255;
        return p;
    };
    short* Wqt_h = (short*)alloc((size_t)1024 * 1024 * 2);
    short* Wqt_l = (short*)alloc((size_t)1024 * 1024 * 2);
    short* Wkt_h = (short*)alloc((size_t)1024 * 1024 * 2);
    short* Wkt_l = (short*)alloc((size_t)1024 * 1024 * 2);
    short* Wvt_h = (short*)alloc((size_t)1024 * 1024 * 2);
    short* Wot_h = (short*)alloc((size_t)1024 * 1024 * 2);
    short* Qhi = (short*)alloc((size_t)4096 * 1024 * 2);
    short* Qlo = (short*)alloc((size_t)4096 * 1024 * 2);
    short* Khi = (short*)alloc((size_t)4096 * 1024 * 2);
    short* Klo = (short*)alloc((size_t)4096 * 1024 * 2);
    short* Vbf = (short*)alloc((size_t)4096 * 1024 * 2);
    short* QQh = (short*)alloc((size_t)4096 * 1024 * 2);
    short* QQl = (short*)alloc((size_t)4096 * 1024 * 2);
    short* KKh = (short*)alloc((size_t)4096 * 1024 * 2);
    short* KKl = (short*)alloc((size_t)4096 * 1024 * 2);
    short* VV  = (short*)alloc((size_t)4096 * 1024 * 2);
    short* VT  = (short*)alloc((size_t)2048 * 2048 * 2 * 2);
    short* CTX = (short*)alloc((size_t)4096 * 1024 * 2);

    dim3 tgrid(32, 32);
    transpose_split_kernel<<<tgrid, 256, 0, stream>>>(Wq, Wqt_h, Wqt_l);
    transpose_split_kernel<<<tgrid, 256, 0, stream>>>(Wk, Wkt_h, Wkt_l);
    transpose_split_kernel<<<tgrid, 256, 0, stream>>>(Wv, Wvt_h, nullptr);
    transpose_split_kernel<<<tgrid, 256, 0, stream>>>(Wo, Wot_h, nullptr);

    split_kernel<<<2048, 256, 0, stream>>>(q, Qhi, Qlo, 4096 * 1024 / 8);
    split_kernel<<<2048, 256, 0, stream>>>(k, Khi, Klo, 4096 * 1024 / 8);
    split_kernel<<<2047, 256, 0, stream>>>(v, Vbf, nullptr, 4094 * 1024 / 8);

    dim3 ggrid(16, 32);  // (N/64, M/128)
    // QQ scaled by log2(e)/8 so attention softmax can use native exp2.
    const float qscale = 0.125f * 1.44269504088896341f;
    gemm_dma<1, 2><<<ggrid, 256, 0, stream>>>(Qhi, Qlo, 4096, Wqt_h, Wqt_l, bq, qscale,
                                              nullptr, QQh, QQl);
    gemm_dma<1, 2><<<ggrid, 256, 0, stream>>>(Khi, Klo, 4096, Wkt_h, Wkt_l, bk, 1.0f,
                                              nullptr, KKh, KKl);
    gemm_dma<0, 1><<<ggrid, 256, 0, stream>>>(Vbf, nullptr, 4094, Wvt_h, nullptr, bv, 1.0f,
                                              nullptr, VV, nullptr);

    transpose_v_kernel<<<dim3(32 * 32), 256, 0, stream>>>(VV, VT);

    attn_kernel<<<dim3(32 * 32), 256, 0, stream>>>(QQh, QQl, KKh, KKl, VT, att, CTX);

    gemm_dma<0, 0><<<ggrid, 256, 0, stream>>>(CTX, nullptr, 4094, Wot_h, nullptr, bo, 1.0f,
                                              out, nullptr, nullptr);
}